// Round 1
// baseline (2282.562 us; speedup 1.0000x reference)
//
#include <hip/hip_runtime.h>
#include <hip/hip_bf16.h>

typedef __bf16 bf16;
typedef __bf16 bf16x8 __attribute__((ext_vector_type(8)));
typedef float f32x4 __attribute__((ext_vector_type(4)));

#define B_ 2
#define S_ 1024
#define D_ 1024
#define L_ 8
#define HQ_ 16
#define HK_ 4
#define DH_ 64
#define FF_ 2816
#define V_ 32000

// ---------------- embedding gather ----------------
__global__ __launch_bounds__(256) void embed_k(const int* __restrict__ toks,
                                               const float* __restrict__ emb,
                                               float* __restrict__ h) {
  int row = blockIdx.x;
  int tok = toks[row];
  f32x4 v = *(const f32x4*)&emb[(size_t)tok * D_ + threadIdx.x * 4];
  *(f32x4*)&h[(size_t)row * D_ + threadIdx.x * 4] = v;
}

// ---------------- rope table: tab[s][d] = {cos, sin} ----------------
__global__ __launch_bounds__(256) void ropetab_k(float* __restrict__ tab) {
  int i = blockIdx.x * 256 + threadIdx.x;
  if (i >= S_ * 32) return;
  int d = i & 31, s = i >> 5;
  float f = expf(-(2.0f * d / 64.0f) * logf(500000.0f));
  float ang = (float)s * f;
  tab[i * 2]     = cosf(ang);
  tab[i * 2 + 1] = sinf(ang);
}

// ---------------- rmsnorm: fp32 in -> bf16 out ----------------
__global__ __launch_bounds__(256) void rmsnorm_k(const float* __restrict__ x,
                                                 const float* __restrict__ w,
                                                 bf16* __restrict__ out) {
  int row = blockIdx.x;
  const float* xr = x + (size_t)row * D_;
  int base = threadIdx.x * 4;
  f32x4 v = *(const f32x4*)&xr[base];
  float ss = v[0]*v[0] + v[1]*v[1] + v[2]*v[2] + v[3]*v[3];
  for (int m = 1; m < 64; m <<= 1) ss += __shfl_xor(ss, m, 64);
  __shared__ float partial[4];
  if ((threadIdx.x & 63) == 0) partial[threadIdx.x >> 6] = ss;
  __syncthreads();
  float tot = partial[0] + partial[1] + partial[2] + partial[3];
  float rr = rsqrtf(tot * (1.0f / D_) + 1e-5f);
  f32x4 wv = *(const f32x4*)&w[base];
  bf16* o = out + (size_t)row * D_ + base;
  o[0] = (bf16)(v[0] * rr * wv[0]);
  o[1] = (bf16)(v[1] * rr * wv[1]);
  o[2] = (bf16)(v[2] * rr * wv[2]);
  o[3] = (bf16)(v[3] * rr * wv[3]);
}

// ---------------- transpose + fp32->bf16:  src[K][N] -> dst[N][K] ----------------
__global__ __launch_bounds__(256) void transpose_cvt(const float* __restrict__ src,
                                                     bf16* __restrict__ dst,
                                                     int K, int N,
                                                     long long srcStride, long long dstStride) {
  __shared__ float tile[32][33];
  int bx = blockIdx.x, by = blockIdx.y, z = blockIdx.z;
  src += (size_t)z * srcStride;
  dst += (size_t)z * dstStride;
  int tx = threadIdx.x & 31, ty = threadIdx.x >> 5;
#pragma unroll
  for (int i = 0; i < 4; ++i) {
    int r = ty + i * 8;
    tile[r][tx] = src[(size_t)(by * 32 + r) * N + bx * 32 + tx];
  }
  __syncthreads();
#pragma unroll
  for (int i = 0; i < 4; ++i) {
    int r = ty + i * 8;
    dst[(size_t)(bx * 32 + r) * K + by * 32 + tx] = (bf16)tile[tx][r];
  }
}

// ---------------- GEMM: C[M][N] = A[M][K](bf16) * BT[N][K](bf16) ----------------
// EPI 0: fp32 out.  EPI 1: fp32 out = acc + R (residual, may alias Cout).  EPI 2: bf16 out.
template <int EPI>
__global__ __launch_bounds__(256) void gemm_bt(const bf16* __restrict__ A,
                                               const bf16* __restrict__ BT,
                                               void* __restrict__ Cout,
                                               const float* __restrict__ R,
                                               int M, int N, int K) {
  __shared__ bf16 As[128 * 64];
  __shared__ bf16 Bs[128 * 64];
  const int t = threadIdx.x;
  const int w = t >> 6, l = t & 63;
  const int l15 = l & 15, l4 = l >> 4;
  const int bm = blockIdx.y * 128, bn = blockIdx.x * 128;
  const int wr = w >> 1, wc = w & 1;

  f32x4 acc[4][4] = {};

  for (int k0 = 0; k0 < K; k0 += 64) {
#pragma unroll
    for (int i = 0; i < 4; ++i) {
      int c = i * 256 + t;            // 1024 chunks of 8 elems
      int row = c >> 3, col8 = (c & 7) * 8;
      *(bf16x8*)&As[row * 64 + col8] = *(const bf16x8*)&A[(size_t)(bm + row) * K + k0 + col8];
      *(bf16x8*)&Bs[row * 64 + col8] = *(const bf16x8*)&BT[(size_t)(bn + row) * K + k0 + col8];
    }
    __syncthreads();
#pragma unroll
    for (int kc = 0; kc < 2; ++kc) {
      bf16x8 af[4], bfr[4];
#pragma unroll
      for (int m = 0; m < 4; ++m)
        af[m] = *(const bf16x8*)&As[(wr * 64 + m * 16 + l15) * 64 + kc * 32 + l4 * 8];
#pragma unroll
      for (int n = 0; n < 4; ++n)
        bfr[n] = *(const bf16x8*)&Bs[(wc * 64 + n * 16 + l15) * 64 + kc * 32 + l4 * 8];
#pragma unroll
      for (int m = 0; m < 4; ++m)
#pragma unroll
        for (int n = 0; n < 4; ++n)
          acc[m][n] = __builtin_amdgcn_mfma_f32_16x16x32_bf16(af[m], bfr[n], acc[m][n], 0, 0, 0);
    }
    __syncthreads();
  }

#pragma unroll
  for (int m = 0; m < 4; ++m)
#pragma unroll
    for (int n = 0; n < 4; ++n)
#pragma unroll
      for (int r = 0; r < 4; ++r) {
        int row = bm + wr * 64 + m * 16 + l4 * 4 + r;
        int col = bn + wc * 64 + n * 16 + l15;
        size_t ix = (size_t)row * N + col;
        float v = acc[m][n][r];
        if (EPI == 0)      ((float*)Cout)[ix] = v;
        else if (EPI == 1) ((float*)Cout)[ix] = v + R[ix];
        else               ((bf16*)Cout)[ix] = (bf16)v;
      }
}

// ---------------- rope on q: qkv[B*S][1536] -> q_r[b,h,s,dh] bf16 ----------------
__global__ __launch_bounds__(256) void rope_q_k(const bf16* __restrict__ qkv,
                                                const float* __restrict__ tab,
                                                bf16* __restrict__ q_r) {
  int i = blockIdx.x * 256 + threadIdx.x;     // pair index, 2^20 total
  int d = i & 31, h = (i >> 5) & 15, s = (i >> 9) & 1023, b = i >> 19;
  size_t src = (size_t)(b * S_ + s) * 1536 + h * 64 + 2 * d;
  float a  = (float)qkv[src];
  float bb = (float)qkv[src + 1];
  float c  = tab[(s * 32 + d) * 2];
  float sn = tab[(s * 32 + d) * 2 + 1];
  size_t o = ((size_t)((b * HQ_ + h) * S_ + s)) * 64 + 2 * d;
  q_r[o]     = (bf16)(a * c - bb * sn);
  q_r[o + 1] = (bf16)(a * sn + bb * c);
}

// ---------------- rope on k ----------------
__global__ __launch_bounds__(256) void rope_k_k(const bf16* __restrict__ qkv,
                                                const float* __restrict__ tab,
                                                bf16* __restrict__ k_r) {
  int i = blockIdx.x * 256 + threadIdx.x;     // 2^18 total
  int d = i & 31, h = (i >> 5) & 3, s = (i >> 7) & 1023, b = i >> 17;
  size_t src = (size_t)(b * S_ + s) * 1536 + 1024 + h * 64 + 2 * d;
  float a  = (float)qkv[src];
  float bb = (float)qkv[src + 1];
  float c  = tab[(s * 32 + d) * 2];
  float sn = tab[(s * 32 + d) * 2 + 1];
  size_t o = ((size_t)((b * HK_ + h) * S_ + s)) * 64 + 2 * d;
  k_r[o]     = (bf16)(a * c - bb * sn);
  k_r[o + 1] = (bf16)(a * sn + bb * c);
}

// ---------------- v transpose: qkv v-cols -> vT[b,h,dh,s] bf16 ----------------
__global__ __launch_bounds__(256) void vtr_k(const bf16* __restrict__ qkv,
                                             bf16* __restrict__ vT) {
  int i = blockIdx.x * 256 + threadIdx.x;     // 2^19 total
  int s = i & 1023, dh = (i >> 10) & 63, h = (i >> 16) & 3, b = i >> 18;
  vT[((size_t)((b * HK_ + h) * 64 + dh)) * S_ + s] =
      qkv[(size_t)(b * S_ + s) * 1536 + 1280 + h * 64 + dh];
}

// ---------------- flash attention (causal, GQA) ----------------
__global__ __launch_bounds__(256) void attn_k(const bf16* __restrict__ q_r,
                                              const bf16* __restrict__ k_r,
                                              const bf16* __restrict__ vT,
                                              bf16* __restrict__ o) {
  __shared__ bf16 k_lds[64 * 64];       // [kpos][dh]
  __shared__ bf16 v_lds[64 * 64];       // [dh][kpos]
  __shared__ bf16 p_lds[4][16 * 72];    // per-wave [16 q][64 k + pad]
  int t = threadIdx.x, w = t >> 6, l = t & 63, l15 = l & 15, l4 = l >> 4;
  int qt = blockIdx.x & 15, head = (blockIdx.x >> 4) & 15, b = blockIdx.x >> 8;
  int kvh = head >> 2;
  const bf16* qh = q_r + ((size_t)(b * HQ_ + head)) * S_ * 64;
  const bf16* kh = k_r + ((size_t)(b * HK_ + kvh)) * S_ * 64;
  const bf16* vh = vT + ((size_t)(b * HK_ + kvh)) * 64 * S_;
  int q0 = qt * 64 + w * 16;

  bf16x8 aq[2];
  aq[0] = *(const bf16x8*)&qh[(size_t)(q0 + l15) * 64 + l4 * 8];
  aq[1] = *(const bf16x8*)&qh[(size_t)(q0 + l15) * 64 + 32 + l4 * 8];

  f32x4 acc_o[4] = {};
  float m_run[4], l_run[4];
#pragma unroll
  for (int r = 0; r < 4; ++r) { m_run[r] = -1e30f; l_run[r] = 0.f; }

  for (int kt = 0; kt <= qt; ++kt) {
    {
      const bf16* src = kh + kt * 4096;
#pragma unroll
      for (int i = 0; i < 2; ++i) {
        int c = i * 256 + t;
        *(bf16x8*)&k_lds[c * 8] = *(const bf16x8*)&src[c * 8];
      }
#pragma unroll
      for (int i = 0; i < 2; ++i) {
        int c = i * 256 + t;
        int row = c >> 3, col8 = (c & 7) * 8;
        *(bf16x8*)&v_lds[row * 64 + col8] = *(const bf16x8*)&vh[(size_t)row * S_ + kt * 64 + col8];
      }
    }
    __syncthreads();

    // QK^T
    f32x4 sc[4];
#pragma unroll
    for (int nt = 0; nt < 4; ++nt) {
      f32x4 a = {};
#pragma unroll
      for (int kc = 0; kc < 2; ++kc) {
        bf16x8 bk = *(const bf16x8*)&k_lds[(nt * 16 + l15) * 64 + kc * 32 + l4 * 8];
        a = __builtin_amdgcn_mfma_f32_16x16x32_bf16(aq[kc], bk, a, 0, 0, 0);
      }
      sc[nt] = a;
    }

    bool diag = (kt == qt);
#pragma unroll
    for (int r = 0; r < 4; ++r) {
      float mx = -1e30f;
#pragma unroll
      for (int nt = 0; nt < 4; ++nt) {
        float s = sc[nt][r] * 0.125f;
        if (diag) {
          int kj = nt * 16 + l15;
          int qi = w * 16 + l4 * 4 + r;
          if (kj > qi) s = -1e30f;
        }
        sc[nt][r] = s;
        mx = fmaxf(mx, s);
      }
      mx = fmaxf(mx, __shfl_xor(mx, 1, 64));
      mx = fmaxf(mx, __shfl_xor(mx, 2, 64));
      mx = fmaxf(mx, __shfl_xor(mx, 4, 64));
      mx = fmaxf(mx, __shfl_xor(mx, 8, 64));
      float mn = fmaxf(m_run[r], mx);
      float scale = __expf(m_run[r] - mn);
      m_run[r] = mn;
      float rs = 0.f;
#pragma unroll
      for (int nt = 0; nt < 4; ++nt) {
        float p = __expf(sc[nt][r] - mn);
        sc[nt][r] = p;
        rs += p;
      }
      rs += __shfl_xor(rs, 1, 64);
      rs += __shfl_xor(rs, 2, 64);
      rs += __shfl_xor(rs, 4, 64);
      rs += __shfl_xor(rs, 8, 64);
      l_run[r] = l_run[r] * scale + rs;
#pragma unroll
      for (int nt = 0; nt < 4; ++nt) acc_o[nt][r] *= scale;
    }

    // P -> LDS (per-wave region), then PV
#pragma unroll
    for (int nt = 0; nt < 4; ++nt)
#pragma unroll
      for (int r = 0; r < 4; ++r)
        p_lds[w][(l4 * 4 + r) * 72 + nt * 16 + l15] = (bf16)sc[nt][r];
    asm volatile("s_waitcnt lgkmcnt(0)" ::: "memory");
    __builtin_amdgcn_sched_barrier(0);

#pragma unroll
    for (int kc = 0; kc < 2; ++kc) {
      bf16x8 pf = *(const bf16x8*)&p_lds[w][l15 * 72 + kc * 32 + l4 * 8];
#pragma unroll
      for (int nt = 0; nt < 4; ++nt) {
        bf16x8 vf = *(const bf16x8*)&v_lds[(nt * 16 + l15) * 64 + kc * 32 + l4 * 8];
        acc_o[nt] = __builtin_amdgcn_mfma_f32_16x16x32_bf16(pf, vf, acc_o[nt], 0, 0, 0);
      }
    }
    __syncthreads();
  }

#pragma unroll
  for (int nt = 0; nt < 4; ++nt)
#pragma unroll
    for (int r = 0; r < 4; ++r) {
      float ov = acc_o[nt][r] / l_run[r];
      int s = qt * 64 + w * 16 + l4 * 4 + r;
      o[((size_t)(b * S_ + s)) * D_ + head * 64 + nt * 16 + l15] = (bf16)ov;
    }
}

// ---------------- silu(ff1) * ff3 -> gate bf16 ----------------
__global__ __launch_bounds__(256) void silumul_k(const bf16* __restrict__ ff,
                                                 bf16* __restrict__ gate) {
  int p = blockIdx.x * 256 + threadIdx.x;    // 720896 total
  int row = p / 352;
  int j = (p % 352) * 8;
  bf16x8 a = *(const bf16x8*)&ff[(size_t)row * 5632 + j];
  bf16x8 c = *(const bf16x8*)&ff[(size_t)row * 5632 + 2816 + j];
  bf16x8 g;
#pragma unroll
  for (int i = 0; i < 8; ++i) {
    float x = (float)a[i];
    float s = x / (1.0f + __expf(-x));
    g[i] = (bf16)(s * (float)c[i]);
  }
  *(bf16x8*)&gate[(size_t)row * 2816 + j] = g;
}

// =======================================================================
extern "C" void kernel_launch(void* const* d_in, const int* in_sizes, int n_in,
                              void* d_out, int out_size, void* d_ws, size_t ws_size,
                              hipStream_t stream) {
  const int* tokens  = (const int*)d_in[0];
  const float* tok_emb = (const float*)d_in[2];
  const float* wq = (const float*)d_in[3];
  const float* wk = (const float*)d_in[4];
  const float* wv = (const float*)d_in[5];
  const float* wo = (const float*)d_in[6];
  const float* w1 = (const float*)d_in[7];
  const float* w2 = (const float*)d_in[8];
  const float* w3 = (const float*)d_in[9];
  const float* anw = (const float*)d_in[10];
  const float* fnw = (const float*)d_in[11];
  const float* finw = (const float*)d_in[12];
  const float* outw = (const float*)d_in[13];

  auto al = [](size_t x) { return (x + 255) & ~(size_t)255; };
  const size_t WTB   = 11272192ull * 2;   // per-layer transposed weights (bf16)
  const size_t OUTWTB = (size_t)V_ * D_ * 2;
  const size_t HB   = (size_t)B_ * S_ * D_ * 4;
  const size_t XBB  = (size_t)B_ * S_ * D_ * 2;
  const size_t QKVB = (size_t)B_ * S_ * 1536 * 2;
  const size_t QRB  = (size_t)B_ * HQ_ * S_ * 64 * 2;
  const size_t KRB  = (size_t)B_ * HK_ * S_ * 64 * 2;
  const size_t OB   = (size_t)B_ * S_ * D_ * 2;
  const size_t FFB  = (size_t)B_ * S_ * 5632 * 2;
  const size_t GATEB = (size_t)B_ * S_ * 2816 * 2;
  const size_t TABB = (size_t)S_ * 32 * 2 * 4;

  size_t fixed = al(OUTWTB) + al(HB) + al(XBB) + al(QKVB) + al(QRB) + al(KRB) + al(KRB) +
                 al(OB) + al(FFB) + al(GATEB) + al(TABB);
  bool allup = ws_size >= fixed + 8 * al(WTB) + 4096;
  int nslots = allup ? 8 : 1;

  char* p = (char*)d_ws;
  bf16* wT    = (bf16*)p; p += (size_t)nslots * al(WTB);
  bf16* outwT = (bf16*)p; p += al(OUTWTB);
  float* h    = (float*)p; p += al(HB);
  bf16* xb    = (bf16*)p; p += al(XBB);
  bf16* qkv   = (bf16*)p; p += al(QKVB);
  bf16* q_r   = (bf16*)p; p += al(QRB);
  bf16* k_r   = (bf16*)p; p += al(KRB);
  bf16* vTb   = (bf16*)p; p += al(KRB);
  bf16* ob    = (bf16*)p; p += al(OB);
  bf16* ff    = (bf16*)p; p += al(FFB);
  bf16* gate  = (bf16*)p; p += al(GATEB);
  float* tab  = (float*)p; p += al(TABB);

  const size_t WTS = al(WTB) / 2;   // slot stride in elems
  // offsets within a layer slot (elems)
  const size_t OFF_QKV = 0;
  const size_t OFF_WK  = 1024ull * 1024;
  const size_t OFF_WV  = 1280ull * 1024;
  const size_t OFF_WO  = 1572864ull;
  const size_t OFF_W13 = 2621440ull;
  const size_t OFF_W3  = 2621440ull + 2816ull * 1024;
  const size_t OFF_W2  = 8388608ull;

  auto tr = [&](const float* src, size_t srcStride, bf16* dst, size_t dstStride,
                int Kd, int Nd, int layers) {
    transpose_cvt<<<dim3(Nd / 32, Kd / 32, layers), 256, 0, stream>>>(
        src, dst, Kd, Nd, (long long)srcStride, (long long)dstStride);
  };

  ropetab_k<<<128, 256, 0, stream>>>(tab);
  embed_k<<<B_ * S_, 256, 0, stream>>>(tokens, tok_emb, h);
  tr(outw, 0, outwT, 0, 1024, 32000, 1);

  if (allup) {
    tr(wq, 1024 * 1024, wT + OFF_QKV, WTS, 1024, 1024, 8);
    tr(wk, 1024 * 256,  wT + OFF_WK,  WTS, 1024, 256, 8);
    tr(wv, 1024 * 256,  wT + OFF_WV,  WTS, 1024, 256, 8);
    tr(wo, 1024 * 1024, wT + OFF_WO,  WTS, 1024, 1024, 8);
    tr(w1, 1024 * 2816, wT + OFF_W13, WTS, 1024, 2816, 8);
    tr(w3, 1024 * 2816, wT + OFF_W3,  WTS, 1024, 2816, 8);
    tr(w2, 2816 * 1024, wT + OFF_W2,  WTS, 2816, 1024, 8);
  }

  for (int l = 0; l < L_; ++l) {
    bf16* wtl = wT + (allup ? (size_t)l * WTS : 0);
    if (!allup) {
      tr(wq + (size_t)l * 1024 * 1024, 0, wtl + OFF_QKV, 0, 1024, 1024, 1);
      tr(wk + (size_t)l * 1024 * 256,  0, wtl + OFF_WK,  0, 1024, 256, 1);
      tr(wv + (size_t)l * 1024 * 256,  0, wtl + OFF_WV,  0, 1024, 256, 1);
      tr(wo + (size_t)l * 1024 * 1024, 0, wtl + OFF_WO,  0, 1024, 1024, 1);
      tr(w1 + (size_t)l * 1024 * 2816, 0, wtl + OFF_W13, 0, 1024, 2816, 1);
      tr(w3 + (size_t)l * 1024 * 2816, 0, wtl + OFF_W3,  0, 1024, 2816, 1);
      tr(w2 + (size_t)l * 2816 * 1024, 0, wtl + OFF_W2,  0, 2816, 1024, 1);
    }

    rmsnorm_k<<<B_ * S_, 256, 0, stream>>>(h, anw + l * D_, xb);
    gemm_bt<2><<<dim3(12, 16), 256, 0, stream>>>(xb, wtl + OFF_QKV, qkv, nullptr, 2048, 1536, 1024);
    rope_q_k<<<4096, 256, 0, stream>>>(qkv, tab, q_r);
    rope_k_k<<<1024, 256, 0, stream>>>(qkv, tab, k_r);
    vtr_k<<<2048, 256, 0, stream>>>(qkv, vTb);
    attn_k<<<B_ * HQ_ * (S_ / 64), 256, 0, stream>>>(q_r, k_r, vTb, ob);
    gemm_bt<1><<<dim3(8, 16), 256, 0, stream>>>(ob, wtl + OFF_WO, h, h, 2048, 1024, 1024);
    rmsnorm_k<<<B_ * S_, 256, 0, stream>>>(h, fnw + l * D_, xb);
    gemm_bt<2><<<dim3(44, 16), 256, 0, stream>>>(xb, wtl + OFF_W13, ff, nullptr, 2048, 5632, 1024);
    silumul_k<<<2816, 256, 0, stream>>>(ff, gate);
    gemm_bt<1><<<dim3(8, 16), 256, 0, stream>>>(gate, wtl + OFF_W2, h, h, 2048, 1024, 2816);
  }

  rmsnorm_k<<<B_ * S_, 256, 0, stream>>>(h, finw, xb);
  gemm_bt<0><<<dim3(250, 16), 256, 0, stream>>>(xb, outwT, d_out, nullptr, 2048, 32000, 1024);
}